// Round 14
// baseline (379.926 us; speedup 1.0000x reference)
//
#include <hip/hip_runtime.h>
#include <hip/hip_bf16.h>

// Biattention: x:[8,2048,1024] f32, mask:[8,2048] i32
// out = concat([x, c, x+c, x-c, x*c], -1) where c = softmax(mask(x x^T)) x
//
// R14: scores REVERTED to R12-exact (128^2 d3, symmetrized 2-pass — ~120us;
// R13's 256^2 port regressed: L2-resident operands don't need the streaming
// structure). context: BM=128 x BN=256, grid 512 = 2 rounds so round-2
// K-loops overlap round-1 epilogue write bursts (was one round = fully
// serial 60us burst). Same 2-phase discipline; ladder re-derived for
// 3-load stage units: prologue/boundary vmcnt(3), tail vmcnt(0).

typedef __attribute__((ext_vector_type(8))) _Float16 half8;
typedef __attribute__((ext_vector_type(8))) unsigned short ushort8;
typedef __attribute__((ext_vector_type(4))) float f32x4;

#define SEQ 2048
#define DIM 1024
#define NBATCH 8
#define BK 32

__device__ __forceinline__ unsigned short f2h(float f) {
  union { _Float16 h; unsigned short u; } cv;
  cv.h = (_Float16)f;
  return cv.u;
}
__device__ __forceinline__ float h2f(unsigned short u) {
  union { _Float16 h; unsigned short u; } cv;
  cv.u = u;
  return (float)cv.h;
}

__device__ __forceinline__ void load16(const void* g, void* l) {
  __builtin_amdgcn_global_load_lds(
      (const __attribute__((address_space(1))) unsigned int*)g,
      (__attribute__((address_space(3))) unsigned int*)l, 16, 0, 0);
}

// ---------------- K1: convert + transpose (fp16; emits h, e, hT) ----------------
__global__ __launch_bounds__(256) void k_prep(
    const float* __restrict__ x, unsigned short* __restrict__ xh,
    unsigned short* __restrict__ xe, unsigned short* __restrict__ xT) {
  __shared__ unsigned short tile[32][33];
  int b = blockIdx.z;
  int s0 = blockIdx.x * 32;
  int d0 = blockIdx.y * 32;
  int t = threadIdx.x;
  int r = t >> 3;
  int c4 = (t & 7) * 4;

  long src = (long)(b * SEQ + s0 + r) * DIM + d0 + c4;
  float4 v = *(const float4*)(x + src);
  float vv[4] = {v.x, v.y, v.z, v.w};
  unsigned short hu[4], eu[4];
#pragma unroll
  for (int j = 0; j < 4; ++j) {
    hu[j] = f2h(vv[j]);
    float hf = h2f(hu[j]);
    float lf = h2f(f2h(vv[j] - hf));
    eu[j] = f2h(hf + 2.0f * lf);   // e = fp16(h + 2l)
    tile[r][c4 + j] = hu[j];
  }
  *(ushort4*)(xh + src) = make_ushort4(hu[0], hu[1], hu[2], hu[3]);
  *(ushort4*)(xe + src) = make_ushort4(eu[0], eu[1], eu[2], eu[3]);
  __syncthreads();
  unsigned short tv[4];
#pragma unroll
  for (int j = 0; j < 4; ++j) tv[j] = tile[c4 + j][r];
  long dst = (long)(b * DIM + d0 + r) * SEQ + s0 + c4;
  *(ushort4*)(xT + dst) = make_ushort4(tv[0], tv[1], tv[2], tv[3]);
}

// shared compute macro (R5-exact structure, f16 MFMA) — used by k_scores
#define COMPUTE_TILE(ARR_A, ARR_B, BUF)                                     \
  {                                                                         \
    half8 af[4], bg[4];                                                     \
    _Pragma("unroll") for (int m = 0; m < 4; ++m) {                         \
      int R = wr * 64 + m * 16 + l15;                                       \
      af[m] = *(const half8*)&ARR_A[BUF][R * BK + ((lhi ^ ((R >> 1) & 3)) * 8)]; \
    }                                                                       \
    _Pragma("unroll") for (int n = 0; n < 4; ++n) {                         \
      int R = wc * 64 + n * 16 + l15;                                       \
      bg[n] = *(const half8*)&ARR_B[BUF][R * BK + ((lhi ^ ((R >> 1) & 3)) * 8)]; \
    }                                                                       \
    _Pragma("unroll") for (int m = 0; m < 4; ++m)                           \
      _Pragma("unroll") for (int n = 0; n < 4; ++n)                         \
        acc[m][n] = __builtin_amdgcn_mfma_f32_16x16x32_f16(af[m], bg[n], acc[m][n], 0, 0, 0); \
  }

// ---------------- K2: scores GEMM (R12-exact: 128^2, symmetrized 2-pass, d3) ----------------
#define NT_SC 64
__global__ __launch_bounds__(256) void k_scores(
    const unsigned short* __restrict__ xh, const unsigned short* __restrict__ xe,
    unsigned short* __restrict__ S) {
  __shared__ unsigned short As[3][128 * BK];
  __shared__ unsigned short Bs[3][128 * BK];
  int p = blockIdx.x + 136 * blockIdx.z;   // 0..1087
  int b = p & 7;                            // one batch per XCD (T1)
  int t = p >> 3;                           // tri-index 0..135
  int bm = 0, rem = 16;
  while (t >= rem) { t -= rem; ++bm; --rem; }
  int bn = bm + t;
  int m0 = bm * 128;
  int n0 = bn * 128;
  const unsigned short* xh_b = xh + (long)b * SEQ * DIM;
  const unsigned short* xe_b = xe + (long)b * SEQ * DIM;
  unsigned short* S_b = S + (long)b * SEQ * SEQ;

  int tid = threadIdx.x;
  int w = tid >> 6, lane = tid & 63;
  int wr = w >> 1, wc = w & 1;
  int l15 = lane & 15, lhi = lane >> 4;

  int cbase0 = w * 64, cbase1 = 256 + w * 64;
  int c0 = cbase0 + lane, c1 = cbase1 + lane;
  int row0 = c0 >> 2, row1 = c1 >> 2;
  long aoff0 = (long)(m0 + row0) * DIM + ((c0 & 3) ^ ((row0 >> 1) & 3)) * 8;
  long aoff1 = (long)(m0 + row1) * DIM + ((c1 & 3) ^ ((row1 >> 1) & 3)) * 8;
  long boff0 = (long)(n0 + row0) * DIM + ((c0 & 3) ^ ((row0 >> 1) & 3)) * 8;
  long boff1 = (long)(n0 + row1) * DIM + ((c1 & 3) ^ ((row1 >> 1) & 3)) * 8;

#define STAGE_SC(KT, BUF)                                                   \
  {                                                                         \
    int pp_ = (KT) >> 5;                 /* 0: A=h,B=e   1: A=e,B=h */      \
    int kk_ = ((KT) & 31) * BK;                                             \
    const unsigned short* As_ = pp_ ? xe_b : xh_b;                          \
    const unsigned short* Bs_ = pp_ ? xh_b : xe_b;                          \
    load16(As_ + aoff0 + kk_, &As[BUF][cbase0 * 8]);                        \
    load16(As_ + aoff1 + kk_, &As[BUF][cbase1 * 8]);                        \
    load16(Bs_ + boff0 + kk_, &Bs[BUF][cbase0 * 8]);                        \
    load16(Bs_ + boff1 + kk_, &Bs[BUF][cbase1 * 8]);                        \
  }

  f32x4 acc[4][4];
#pragma unroll
  for (int m = 0; m < 4; ++m)
#pragma unroll
    for (int n = 0; n < 4; ++n)
#pragma unroll
      for (int j = 0; j < 4; ++j) acc[m][n][j] = 0.0f;

  STAGE_SC(0, 0);
  STAGE_SC(1, 1);
  STAGE_SC(2, 2);
  int cur = 0;
  for (int kt = 0; kt < NT_SC - 2; ++kt) {
    asm volatile("s_waitcnt vmcnt(8)" ::: "memory");
    __builtin_amdgcn_s_barrier();
    __builtin_amdgcn_sched_barrier(0);
    COMPUTE_TILE(As, Bs, cur);
    __builtin_amdgcn_sched_barrier(0);
    __builtin_amdgcn_s_barrier();
    if (kt + 3 < NT_SC) STAGE_SC(kt + 3, cur);
    cur = (cur == 2) ? 0 : cur + 1;
  }
  asm volatile("s_waitcnt vmcnt(4)" ::: "memory");
  __builtin_amdgcn_s_barrier();
  COMPUTE_TILE(As, Bs, (NT_SC - 2) % 3);
  asm volatile("s_waitcnt vmcnt(0)" ::: "memory");
  __builtin_amdgcn_s_barrier();
  COMPUTE_TILE(As, Bs, (NT_SC - 1) % 3);

  // normal-orientation write (scalar fp16), S = 0.5 * acc
#pragma unroll
  for (int m = 0; m < 4; ++m)
#pragma unroll
    for (int n = 0; n < 4; ++n)
#pragma unroll
      for (int j = 0; j < 4; ++j) {
        int r = m0 + wr * 64 + m * 16 + lhi * 4 + j;
        int c = n0 + wc * 64 + n * 16 + l15;
        S_b[(long)r * SEQ + c] = f2h(0.5f * acc[m][n][j]);
      }
  // transposed write for off-diagonal blocks
  if (bm != bn) {
#pragma unroll
    for (int m = 0; m < 4; ++m)
#pragma unroll
      for (int n = 0; n < 4; ++n) {
        int r0 = m0 + wr * 64 + m * 16 + lhi * 4;
        int c = n0 + wc * 64 + n * 16 + l15;
        *(ushort4*)&S_b[(long)c * SEQ + r0] = make_ushort4(
            f2h(0.5f * acc[m][n][0]), f2h(0.5f * acc[m][n][1]),
            f2h(0.5f * acc[m][n][2]), f2h(0.5f * acc[m][n][3]));
      }
  }
}

// ---------------- K3: masked softmax (fp16 in, fp16 out), wave per row ----------------
__global__ __launch_bounds__(256) void k_softmax(
    const unsigned short* __restrict__ S, const int* __restrict__ mask,
    unsigned short* __restrict__ P) {
  int w = threadIdx.x >> 6, lane = threadIdx.x & 63;
  long row = (long)blockIdx.x * 4 + w;
  int b = (int)(row >> 11);
  const unsigned short* Sp = S + row * SEQ;
  const int* mp = mask + b * SEQ;
  unsigned short* Pp = P + row * SEQ;

  float sv[32];
  float mx = -__builtin_inff();
#pragma unroll
  for (int ci = 0; ci < 4; ++ci) {
    int col = ci * 512 + lane * 8;
    ushort8 v = *(const ushort8*)(Sp + col);
    int4 ma = *(const int4*)(mp + col);
    int4 mb = *(const int4*)(mp + col + 4);
    int mk[8] = {ma.x, ma.y, ma.z, ma.w, mb.x, mb.y, mb.z, mb.w};
#pragma unroll
    for (int j = 0; j < 8; ++j) {
      float s = mk[j] ? h2f(v[j]) : -__builtin_inff();
      sv[ci * 8 + j] = s;
      mx = fmaxf(mx, s);
    }
  }
#pragma unroll
  for (int off = 32; off; off >>= 1) mx = fmaxf(mx, __shfl_xor(mx, off));
  float pv[32];
  float sum = 0.0f;
#pragma unroll
  for (int i = 0; i < 32; ++i) {
    pv[i] = expf(sv[i] - mx);
    sum += pv[i];
  }
#pragma unroll
  for (int off = 32; off; off >>= 1) sum += __shfl_xor(sum, off);
  float inv = 1.0f / sum;
#pragma unroll
  for (int ci = 0; ci < 4; ++ci) {
    int col = ci * 512 + lane * 8;
    ushort8 o;
#pragma unroll
    for (int j = 0; j < 8; ++j) o[j] = f2h(pv[ci * 8 + j] * inv);
    *(ushort8*)(Pp + col) = o;
  }
}

// ---------------- K4: context GEMM BM=128 x BN=256, BK=64, 2 phases/tile ----------------
// grid 512 = 8 batch * (16 m x 4 n) -> 2 rounds; round-2 K-loop overlaps
// round-1 epilogue. 8 waves 2Mx4N, per-wave 64x64, acc[4][4].
// LDS: As[2buf][2kk][128][32] = 32KB, Bs[2][2][256][32] = 64KB -> 96KB.
// Stage unit per kk-half = 3 loads (A:1 + B:2) -> vmcnt(3) ladder.
#define NT_CTX 32
__global__ __launch_bounds__(512, 2) void k_context(
    const unsigned short* __restrict__ P, const unsigned short* __restrict__ xT,
    const float* __restrict__ x, float* __restrict__ out) {
  __shared__ unsigned short As[2 * 8192];    // 32 KB
  __shared__ unsigned short Bs[2 * 16384];   // 64 KB
  int p = blockIdx.x;            // 0..511
  int b = p & 7;                 // one batch per XCD (T1)
  int q = p >> 3;                // 0..63
  int n0 = (q & 3) * 256;        // d cols
  int m0 = (q >> 2) * 128;       // q rows (16 m-tiles)
  const unsigned short* A_b = P + (long)b * SEQ * SEQ;
  const unsigned short* B_b = xT + (long)b * DIM * SEQ;

  int tid = threadIdx.x;
  int w = tid >> 6, lane = tid & 63;
  int wr = w >> 2, wc = w & 3;          // 2M x 4N waves; per-wave 64x64
  int l15 = lane & 15, lhi = lane >> 4;

  // A staging: per kk-half 512 chunks, 1/thread
  int cA = w * 64 + lane;
  int RA = cA >> 2;
  int swA = ((cA & 3) ^ ((RA >> 1) & 3)) * 8;
  const unsigned short* PA = A_b + (long)(m0 + RA) * SEQ + swA;
  int ldgA = (w * 64) * 8;
  // B staging: per kk-half 1024 chunks, 2/thread
  int cB0 = w * 128 + lane, cB1 = w * 128 + 64 + lane;
  int RB0 = cB0 >> 2, RB1 = cB1 >> 2;
  int swB0 = ((cB0 & 3) ^ ((RB0 >> 1) & 3)) * 8;
  int swB1 = ((cB1 & 3) ^ ((RB1 >> 1) & 3)) * 8;
  const unsigned short* PB0 = B_b + (long)(n0 + RB0) * SEQ + swB0;
  const unsigned short* PB1 = B_b + (long)(n0 + RB1) * SEQ + swB1;
  int ldgB0 = (w * 128) * 8;
  int ldgB1 = (w * 128 + 64) * 8;

#define CSTG(KT, KK, BUF)                                                    \
  {                                                                          \
    load16(PA + (KT) * 64 + (KK) * 32, &As[(BUF)*8192 + (KK)*4096 + ldgA]);  \
    load16(PB0 + (KT) * 64 + (KK) * 32, &Bs[(BUF)*16384 + (KK)*8192 + ldgB0]); \
    load16(PB1 + (KT) * 64 + (KK) * 32, &Bs[(BUF)*16384 + (KK)*8192 + ldgB1]); \
  }

  int swr = (lhi ^ ((l15 >> 1) & 3)) * 8;
  int arow = (wr * 64 + l15) * 32;
  int brow = (wc * 64 + l15) * 32;

  // one kk-half phase: 8 frag reads, 3 staged loads, PH discipline, 16 MFMA
#define CPHASE(BUF, KK, DO_STG, STKT, STKK, STBUF)                            \
  {                                                                           \
    half8 af[4], bg[4];                                                       \
    _Pragma("unroll") for (int n = 0; n < 4; ++n)                             \
        bg[n] = *(const half8*)&Bs[(BUF)*16384 + (KK)*8192 + brow + n * 512 + swr]; \
    _Pragma("unroll") for (int m = 0; m < 4; ++m)                             \
        af[m] = *(const half8*)&As[(BUF)*8192 + (KK)*4096 + arow + m * 512 + swr]; \
    if (DO_STG) CSTG(STKT, STKK, STBUF);                                      \
    __builtin_amdgcn_s_barrier();                                             \
    asm volatile("s_waitcnt lgkmcnt(0)" ::: "memory");                        \
    __builtin_amdgcn_sched_barrier(0);                                        \
    __builtin_amdgcn_s_setprio(1);                                            \
    _Pragma("unroll") for (int m = 0; m < 4; ++m)                             \
      _Pragma("unroll") for (int n = 0; n < 4; ++n)                           \
        acc[m][n] = __builtin_amdgcn_mfma_f32_16x16x32_f16(                   \
            bg[n], af[m], acc[m][n], 0, 0, 0);                                \
    __builtin_amdgcn_s_setprio(0);                                            \
    __builtin_amdgcn_sched_barrier(0);                                        \
  }

  f32x4 acc[4][4];
#pragma unroll
  for (int m = 0; m < 4; ++m)
#pragma unroll
    for (int n = 0; n < 4; ++n)
#pragma unroll
      for (int j = 0; j < 4; ++j) acc[m][n][j] = 0.0f;

  // prologue: kt0 full (6 loads) + kt1 kk0 (3); drain kt0 -> vmcnt(3)
  CSTG(0, 0, 0);
  CSTG(0, 1, 0);
  CSTG(1, 0, 1);
  asm volatile("s_waitcnt vmcnt(3)" ::: "memory");
  __builtin_amdgcn_s_barrier();

  for (int kt = 0; kt < NT_CTX; ++kt) {
    int c = kt & 1, o = c ^ 1;
    int haveN1 = (kt + 1 < NT_CTX), haveN2 = (kt + 2 < NT_CTX);
    // phase A: compute kk0 of c; stage kt+1-kk1 -> o
    CPHASE(c, 0, haveN1, kt + 1, 1, o);
    __builtin_amdgcn_s_barrier();   // all waves done reading c-kk0
    // phase B: compute kk1 of c; stage kt+2-kk0 -> c (region just released)
    CPHASE(c, 1, haveN2, kt + 2, 0, c);
    if (kt < NT_CTX - 2) {
      asm volatile("s_waitcnt vmcnt(3)" ::: "memory");  // kt+1 both halves landed
    } else if (kt == NT_CTX - 2) {
      asm volatile("s_waitcnt vmcnt(0)" ::: "memory");
    }
    __builtin_amdgcn_s_barrier();
  }

  // epilogue: swapped-operand C layout -> thread holds 4 consecutive d (f32x4)
  const float* x_b = x + (long)b * SEQ * DIM;
  float* out_b = out + (long)b * SEQ * (5 * DIM);
#pragma unroll
  for (int m = 0; m < 4; ++m)
#pragma unroll
    for (int n = 0; n < 4; ++n) {
      int qi = m0 + wr * 64 + m * 16 + l15;       // col index = q
      int d = n0 + wc * 64 + n * 16 + lhi * 4;    // row index = d (4 consec)
      f32x4 c4 = acc[m][n];
      f32x4 xv = *(const f32x4*)&x_b[(long)qi * DIM + d];
      long base = (long)qi * (5 * DIM) + d;
      *(f32x4*)&out_b[base] = xv;
      *(f32x4*)&out_b[base + DIM] = c4;
      *(f32x4*)&out_b[base + 2 * DIM] = xv + c4;
      *(f32x4*)&out_b[base + 3 * DIM] = xv - c4;
      *(f32x4*)&out_b[base + 4 * DIM] = xv * c4;
    }
}

extern "C" void kernel_launch(void* const* d_in, const int* in_sizes, int n_in,
                              void* d_out, int out_size, void* d_ws, size_t ws_size,
                              hipStream_t stream) {
  const float* x = (const float*)d_in[0];
  const int* mask = (const int*)d_in[1];
  float* out = (float*)d_out;
  char* ws = (char*)d_ws;

  const size_t HB = (size_t)NBATCH * SEQ * DIM * 2;
  unsigned short* xh = (unsigned short*)ws;
  unsigned short* xe = (unsigned short*)(ws + HB);
  unsigned short* xT = (unsigned short*)(ws + 2 * HB);
  unsigned short* P = (unsigned short*)(ws + 3 * HB);
  const size_t PB = (size_t)NBATCH * SEQ * SEQ * 2;
  const size_t SB = (size_t)NBATCH * SEQ * SEQ * 2;   // S fp16
  unsigned short* S;
  if (ws_size >= 3 * HB + PB + SB) {
    S = (unsigned short*)(ws + 3 * HB + PB);
  } else {
    S = (unsigned short*)d_out;  // S dead before K4 writes out
  }

  k_prep<<<dim3(SEQ / 32, DIM / 32, NBATCH), 256, 0, stream>>>(x, xh, xe, xT);
  k_scores<<<dim3(136, 1, NBATCH), 256, 0, stream>>>(xh, xe, S);
  k_softmax<<<NBATCH * SEQ / 4, 256, 0, stream>>>(S, mask, P);
  k_context<<<dim3(512, 1, 1), 512, 0, stream>>>(P, xT, x, out);
}

// Round 15
// 334.817 us; speedup vs baseline: 1.1347x; 1.1347x over previous
//
#include <hip/hip_runtime.h>
#include <hip/hip_bf16.h>

// Biattention: x:[8,2048,1024] f32, mask:[8,2048] i32
// out = concat([x, c, x+c, x-c, x*c], -1) where c = softmax(mask(x x^T)) x
//
// R15 = R12-exact revert (best measured: 355us) + nontemporal stores on the
// context epilogue (output streamed once, never re-read).
// Locked-in structure:
//  prep:    fp16 h / e=fp16(h+2l) / hT           (~30us)
//  scores:  128^2 d3 compiler-scheduled, symmetrized 2-pass S=(h e^T+e h^T)/2,
//           tri-blocks + mirror write, fp16 S     (~120us)
//  softmax: wave/row, fp16 in/out                 (~22us)
//  context: 256^2 BK=64 8-wave 2-phase disciplined (vmcnt(4) ladder), fp16,
//           swapped-op f32x4 epilogue             (~165us)
// T1 batch-per-XCD, T2 swizzle (verified 0 bank conflicts) throughout.

typedef __attribute__((ext_vector_type(8))) _Float16 half8;
typedef __attribute__((ext_vector_type(8))) unsigned short ushort8;
typedef __attribute__((ext_vector_type(4))) float f32x4;

#define SEQ 2048
#define DIM 1024
#define NBATCH 8
#define BK 32

__device__ __forceinline__ unsigned short f2h(float f) {
  union { _Float16 h; unsigned short u; } cv;
  cv.h = (_Float16)f;
  return cv.u;
}
__device__ __forceinline__ float h2f(unsigned short u) {
  union { _Float16 h; unsigned short u; } cv;
  cv.u = u;
  return (float)cv.h;
}

__device__ __forceinline__ void load16(const void* g, void* l) {
  __builtin_amdgcn_global_load_lds(
      (const __attribute__((address_space(1))) unsigned int*)g,
      (__attribute__((address_space(3))) unsigned int*)l, 16, 0, 0);
}

// ---------------- K1: convert + transpose (fp16; emits h, e, hT) ----------------
__global__ __launch_bounds__(256) void k_prep(
    const float* __restrict__ x, unsigned short* __restrict__ xh,
    unsigned short* __restrict__ xe, unsigned short* __restrict__ xT) {
  __shared__ unsigned short tile[32][33];
  int b = blockIdx.z;
  int s0 = blockIdx.x * 32;
  int d0 = blockIdx.y * 32;
  int t = threadIdx.x;
  int r = t >> 3;
  int c4 = (t & 7) * 4;

  long src = (long)(b * SEQ + s0 + r) * DIM + d0 + c4;
  float4 v = *(const float4*)(x + src);
  float vv[4] = {v.x, v.y, v.z, v.w};
  unsigned short hu[4], eu[4];
#pragma unroll
  for (int j = 0; j < 4; ++j) {
    hu[j] = f2h(vv[j]);
    float hf = h2f(hu[j]);
    float lf = h2f(f2h(vv[j] - hf));
    eu[j] = f2h(hf + 2.0f * lf);   // e = fp16(h + 2l)
    tile[r][c4 + j] = hu[j];
  }
  *(ushort4*)(xh + src) = make_ushort4(hu[0], hu[1], hu[2], hu[3]);
  *(ushort4*)(xe + src) = make_ushort4(eu[0], eu[1], eu[2], eu[3]);
  __syncthreads();
  unsigned short tv[4];
#pragma unroll
  for (int j = 0; j < 4; ++j) tv[j] = tile[c4 + j][r];
  long dst = (long)(b * DIM + d0 + r) * SEQ + s0 + c4;
  *(ushort4*)(xT + dst) = make_ushort4(tv[0], tv[1], tv[2], tv[3]);
}

// shared compute macro (R5-exact structure, f16 MFMA) — used by k_scores
#define COMPUTE_TILE(ARR_A, ARR_B, BUF)                                     \
  {                                                                         \
    half8 af[4], bg[4];                                                     \
    _Pragma("unroll") for (int m = 0; m < 4; ++m) {                         \
      int R = wr * 64 + m * 16 + l15;                                       \
      af[m] = *(const half8*)&ARR_A[BUF][R * BK + ((lhi ^ ((R >> 1) & 3)) * 8)]; \
    }                                                                       \
    _Pragma("unroll") for (int n = 0; n < 4; ++n) {                         \
      int R = wc * 64 + n * 16 + l15;                                       \
      bg[n] = *(const half8*)&ARR_B[BUF][R * BK + ((lhi ^ ((R >> 1) & 3)) * 8)]; \
    }                                                                       \
    _Pragma("unroll") for (int m = 0; m < 4; ++m)                           \
      _Pragma("unroll") for (int n = 0; n < 4; ++n)                         \
        acc[m][n] = __builtin_amdgcn_mfma_f32_16x16x32_f16(af[m], bg[n], acc[m][n], 0, 0, 0); \
  }

// ---------------- K2: scores GEMM (128^2, symmetrized 2-pass, d3) ----------------
#define NT_SC 64
__global__ __launch_bounds__(256) void k_scores(
    const unsigned short* __restrict__ xh, const unsigned short* __restrict__ xe,
    unsigned short* __restrict__ S) {
  __shared__ unsigned short As[3][128 * BK];
  __shared__ unsigned short Bs[3][128 * BK];
  int p = blockIdx.x + 136 * blockIdx.z;   // 0..1087
  int b = p & 7;                            // one batch per XCD (T1)
  int t = p >> 3;                           // tri-index 0..135
  int bm = 0, rem = 16;
  while (t >= rem) { t -= rem; ++bm; --rem; }
  int bn = bm + t;
  int m0 = bm * 128;
  int n0 = bn * 128;
  const unsigned short* xh_b = xh + (long)b * SEQ * DIM;
  const unsigned short* xe_b = xe + (long)b * SEQ * DIM;
  unsigned short* S_b = S + (long)b * SEQ * SEQ;

  int tid = threadIdx.x;
  int w = tid >> 6, lane = tid & 63;
  int wr = w >> 1, wc = w & 1;
  int l15 = lane & 15, lhi = lane >> 4;

  int cbase0 = w * 64, cbase1 = 256 + w * 64;
  int c0 = cbase0 + lane, c1 = cbase1 + lane;
  int row0 = c0 >> 2, row1 = c1 >> 2;
  long aoff0 = (long)(m0 + row0) * DIM + ((c0 & 3) ^ ((row0 >> 1) & 3)) * 8;
  long aoff1 = (long)(m0 + row1) * DIM + ((c1 & 3) ^ ((row1 >> 1) & 3)) * 8;
  long boff0 = (long)(n0 + row0) * DIM + ((c0 & 3) ^ ((row0 >> 1) & 3)) * 8;
  long boff1 = (long)(n0 + row1) * DIM + ((c1 & 3) ^ ((row1 >> 1) & 3)) * 8;

#define STAGE_SC(KT, BUF)                                                   \
  {                                                                         \
    int pp_ = (KT) >> 5;                 /* 0: A=h,B=e   1: A=e,B=h */      \
    int kk_ = ((KT) & 31) * BK;                                             \
    const unsigned short* As_ = pp_ ? xe_b : xh_b;                          \
    const unsigned short* Bs_ = pp_ ? xh_b : xe_b;                          \
    load16(As_ + aoff0 + kk_, &As[BUF][cbase0 * 8]);                        \
    load16(As_ + aoff1 + kk_, &As[BUF][cbase1 * 8]);                        \
    load16(Bs_ + boff0 + kk_, &Bs[BUF][cbase0 * 8]);                        \
    load16(Bs_ + boff1 + kk_, &Bs[BUF][cbase1 * 8]);                        \
  }

  f32x4 acc[4][4];
#pragma unroll
  for (int m = 0; m < 4; ++m)
#pragma unroll
    for (int n = 0; n < 4; ++n)
#pragma unroll
      for (int j = 0; j < 4; ++j) acc[m][n][j] = 0.0f;

  STAGE_SC(0, 0);
  STAGE_SC(1, 1);
  STAGE_SC(2, 2);
  int cur = 0;
  for (int kt = 0; kt < NT_SC - 2; ++kt) {
    asm volatile("s_waitcnt vmcnt(8)" ::: "memory");
    __builtin_amdgcn_s_barrier();
    __builtin_amdgcn_sched_barrier(0);
    COMPUTE_TILE(As, Bs, cur);
    __builtin_amdgcn_sched_barrier(0);
    __builtin_amdgcn_s_barrier();
    if (kt + 3 < NT_SC) STAGE_SC(kt + 3, cur);
    cur = (cur == 2) ? 0 : cur + 1;
  }
  asm volatile("s_waitcnt vmcnt(4)" ::: "memory");
  __builtin_amdgcn_s_barrier();
  COMPUTE_TILE(As, Bs, (NT_SC - 2) % 3);
  asm volatile("s_waitcnt vmcnt(0)" ::: "memory");
  __builtin_amdgcn_s_barrier();
  COMPUTE_TILE(As, Bs, (NT_SC - 1) % 3);

  // normal-orientation write (scalar fp16), S = 0.5 * acc
#pragma unroll
  for (int m = 0; m < 4; ++m)
#pragma unroll
    for (int n = 0; n < 4; ++n)
#pragma unroll
      for (int j = 0; j < 4; ++j) {
        int r = m0 + wr * 64 + m * 16 + lhi * 4 + j;
        int c = n0 + wc * 64 + n * 16 + l15;
        S_b[(long)r * SEQ + c] = f2h(0.5f * acc[m][n][j]);
      }
  // transposed write for off-diagonal blocks
  if (bm != bn) {
#pragma unroll
    for (int m = 0; m < 4; ++m)
#pragma unroll
      for (int n = 0; n < 4; ++n) {
        int r0 = m0 + wr * 64 + m * 16 + lhi * 4;
        int c = n0 + wc * 64 + n * 16 + l15;
        *(ushort4*)&S_b[(long)c * SEQ + r0] = make_ushort4(
            f2h(0.5f * acc[m][n][0]), f2h(0.5f * acc[m][n][1]),
            f2h(0.5f * acc[m][n][2]), f2h(0.5f * acc[m][n][3]));
      }
  }
}

// ---------------- K3: masked softmax (fp16 in, fp16 out), wave per row ----------------
__global__ __launch_bounds__(256) void k_softmax(
    const unsigned short* __restrict__ S, const int* __restrict__ mask,
    unsigned short* __restrict__ P) {
  int w = threadIdx.x >> 6, lane = threadIdx.x & 63;
  long row = (long)blockIdx.x * 4 + w;
  int b = (int)(row >> 11);
  const unsigned short* Sp = S + row * SEQ;
  const int* mp = mask + b * SEQ;
  unsigned short* Pp = P + row * SEQ;

  float sv[32];
  float mx = -__builtin_inff();
#pragma unroll
  for (int ci = 0; ci < 4; ++ci) {
    int col = ci * 512 + lane * 8;
    ushort8 v = *(const ushort8*)(Sp + col);
    int4 ma = *(const int4*)(mp + col);
    int4 mb = *(const int4*)(mp + col + 4);
    int mk[8] = {ma.x, ma.y, ma.z, ma.w, mb.x, mb.y, mb.z, mb.w};
#pragma unroll
    for (int j = 0; j < 8; ++j) {
      float s = mk[j] ? h2f(v[j]) : -__builtin_inff();
      sv[ci * 8 + j] = s;
      mx = fmaxf(mx, s);
    }
  }
#pragma unroll
  for (int off = 32; off; off >>= 1) mx = fmaxf(mx, __shfl_xor(mx, off));
  float pv[32];
  float sum = 0.0f;
#pragma unroll
  for (int i = 0; i < 32; ++i) {
    pv[i] = expf(sv[i] - mx);
    sum += pv[i];
  }
#pragma unroll
  for (int off = 32; off; off >>= 1) sum += __shfl_xor(sum, off);
  float inv = 1.0f / sum;
#pragma unroll
  for (int ci = 0; ci < 4; ++ci) {
    int col = ci * 512 + lane * 8;
    ushort8 o;
#pragma unroll
    for (int j = 0; j < 8; ++j) o[j] = f2h(pv[ci * 8 + j] * inv);
    *(ushort8*)(Pp + col) = o;
  }
}

// ---------------- K4: context GEMM 256^2 BK=64, 2 phases/tile (R12-exact) ----------------
// + nontemporal epilogue stores (output never re-read; keep L2 for P/xT)
#define NT_CTX 32
__global__ __launch_bounds__(512, 2) void k_context(
    const unsigned short* __restrict__ P, const unsigned short* __restrict__ xT,
    const float* __restrict__ x, float* __restrict__ out) {
  __shared__ unsigned short As[2 * 16384];  // 64 KB
  __shared__ unsigned short Bs[2 * 16384];  // 64 KB
  int p = blockIdx.x;            // 0..255
  int b = p & 7;                 // one batch per XCD (T1)
  int q = p >> 3;                // 0..31
  int n0 = (q & 3) * 256;        // d cols
  int m0 = (q >> 2) * 256;       // q rows
  const unsigned short* A_b = P + (long)b * SEQ * SEQ;
  const unsigned short* B_b = xT + (long)b * DIM * SEQ;

  int tid = threadIdx.x;
  int w = tid >> 6, lane = tid & 63;
  int wr = w >> 2, wc = w & 3;          // 2M x 4N waves; per-wave 128x64
  int l15 = lane & 15, lhi = lane >> 4;

  int c0 = w * 128 + lane, c1 = w * 128 + 64 + lane;
  int R0 = c0 >> 2, R1 = c1 >> 2;
  int sw0 = ((c0 & 3) ^ ((R0 >> 1) & 3)) * 8;
  int sw1 = ((c1 & 3) ^ ((R1 >> 1) & 3)) * 8;
  const unsigned short* PA0 = A_b + (long)(m0 + R0) * SEQ + sw0;
  const unsigned short* PA1 = A_b + (long)(m0 + R1) * SEQ + sw1;
  const unsigned short* PB0 = B_b + (long)(n0 + R0) * SEQ + sw0;
  const unsigned short* PB1 = B_b + (long)(n0 + R1) * SEQ + sw1;
  int ldg0 = (w * 128) * 8;
  int ldg1 = (w * 128 + 64) * 8;

#define STG_A(KT, KK, BUF)                                              \
  {                                                                     \
    load16(PA0 + (KT) * 64 + (KK) * 32, &As[(BUF)*16384 + (KK)*8192 + ldg0]); \
    load16(PA1 + (KT) * 64 + (KK) * 32, &As[(BUF)*16384 + (KK)*8192 + ldg1]); \
  }
#define STG_B(KT, KK, BUF)                                              \
  {                                                                     \
    load16(PB0 + (KT) * 64 + (KK) * 32, &Bs[(BUF)*16384 + (KK)*8192 + ldg0]); \
    load16(PB1 + (KT) * 64 + (KK) * 32, &Bs[(BUF)*16384 + (KK)*8192 + ldg1]); \
  }

  int swr = (lhi ^ ((l15 >> 1) & 3)) * 8;
  int arow = (wr * 128 + l15) * 32;
  int brow = (wc * 64 + l15) * 32;

  // one kk-half phase: read 12 frags, stage 4 loads, PH discipline, 32 MFMA
#define PHASE_CTX(BUF, KK, DO_STG_A, DO_STG_B, STKT, STKK, STBUF)             \
  {                                                                           \
    half8 af[8], bg[4];                                                       \
    _Pragma("unroll") for (int n = 0; n < 4; ++n)                             \
        bg[n] = *(const half8*)&Bs[(BUF)*16384 + (KK)*8192 + brow + n * 512 + swr]; \
    _Pragma("unroll") for (int m = 0; m < 8; ++m)                             \
        af[m] = *(const half8*)&As[(BUF)*16384 + (KK)*8192 + arow + m * 512 + swr]; \
    if (DO_STG_A) STG_A(STKT, STKK, STBUF);                                   \
    if (DO_STG_B) STG_B(STKT, STKK, STBUF);                                   \
    __builtin_amdgcn_s_barrier();                                             \
    asm volatile("s_waitcnt lgkmcnt(0)" ::: "memory");                        \
    __builtin_amdgcn_sched_barrier(0);                                        \
    __builtin_amdgcn_s_setprio(1);                                            \
    _Pragma("unroll") for (int m = 0; m < 8; ++m)                             \
      _Pragma("unroll") for (int n = 0; n < 4; ++n)                           \
        acc[m][n] = __builtin_amdgcn_mfma_f32_16x16x32_f16(                   \
            bg[n], af[m], acc[m][n], 0, 0, 0);                                \
    __builtin_amdgcn_s_setprio(0);                                            \
    __builtin_amdgcn_sched_barrier(0);                                        \
  }

  f32x4 acc[8][4];
#pragma unroll
  for (int m = 0; m < 8; ++m)
#pragma unroll
    for (int n = 0; n < 4; ++n)
#pragma unroll
      for (int j = 0; j < 4; ++j) acc[m][n][j] = 0.0f;

  // prologue: kt0 full (8 loads) + kt1 kk0 (4 loads); drain kt0 -> vmcnt(4)
  STG_A(0, 0, 0); STG_B(0, 0, 0);
  STG_A(0, 1, 0); STG_B(0, 1, 0);
  STG_A(1, 0, 1); STG_B(1, 0, 1);
  asm volatile("s_waitcnt vmcnt(4)" ::: "memory");
  __builtin_amdgcn_s_barrier();

  for (int kt = 0; kt < NT_CTX; ++kt) {
    int c = kt & 1, o = c ^ 1;
    int haveN1 = (kt + 1 < NT_CTX), haveN2 = (kt + 2 < NT_CTX);
    // phase A: compute kk0 of c; stage kt+1-kk1 -> o
    PHASE_CTX(c, 0, haveN1, haveN1, kt + 1, 1, o);
    __builtin_amdgcn_s_barrier();   // all waves done reading c-kk0
    // phase B: compute kk1 of c; stage kt+2-kk0 -> c (region just released)
    PHASE_CTX(c, 1, haveN2, haveN2, kt + 2, 0, c);
    if (kt < NT_CTX - 2) {
      asm volatile("s_waitcnt vmcnt(4)" ::: "memory");
    } else if (kt == NT_CTX - 2) {
      asm volatile("s_waitcnt vmcnt(0)" ::: "memory");
    }
    __builtin_amdgcn_s_barrier();
  }

  // epilogue: swapped-operand C layout -> thread holds 4 consecutive d (f32x4)
  // nontemporal: output is streamed once, never re-read
  const float* x_b = x + (long)b * SEQ * DIM;
  float* out_b = out + (long)b * SEQ * (5 * DIM);
#pragma unroll
  for (int m = 0; m < 8; ++m)
#pragma unroll
    for (int n = 0; n < 4; ++n) {
      int qi = m0 + wr * 128 + m * 16 + l15;      // col index = q
      int d = n0 + wc * 64 + n * 16 + lhi * 4;    // row index = d (4 consec)
      f32x4 c4 = acc[m][n];
      f32x4 xv = *(const f32x4*)&x_b[(long)qi * DIM + d];
      long base = (long)qi * (5 * DIM) + d;
      __builtin_nontemporal_store(xv,       (f32x4*)&out_b[base]);
      __builtin_nontemporal_store(c4,       (f32x4*)&out_b[base + DIM]);
      __builtin_nontemporal_store(xv + c4,  (f32x4*)&out_b[base + 2 * DIM]);
      __builtin_nontemporal_store(xv - c4,  (f32x4*)&out_b[base + 3 * DIM]);
      __builtin_nontemporal_store(xv * c4,  (f32x4*)&out_b[base + 4 * DIM]);
    }
}

extern "C" void kernel_launch(void* const* d_in, const int* in_sizes, int n_in,
                              void* d_out, int out_size, void* d_ws, size_t ws_size,
                              hipStream_t stream) {
  const float* x = (const float*)d_in[0];
  const int* mask = (const int*)d_in[1];
  float* out = (float*)d_out;
  char* ws = (char*)d_ws;

  const size_t HB = (size_t)NBATCH * SEQ * DIM * 2;
  unsigned short* xh = (unsigned short*)ws;
  unsigned short* xe = (unsigned short*)(ws + HB);
  unsigned short* xT = (unsigned short*)(ws + 2 * HB);
  unsigned short* P = (unsigned short*)(ws + 3 * HB);
  const size_t PB = (size_t)NBATCH * SEQ * SEQ * 2;
  const size_t SB = (size_t)NBATCH * SEQ * SEQ * 2;   // S fp16
  unsigned short* S;
  if (ws_size >= 3 * HB + PB + SB) {
    S = (unsigned short*)(ws + 3 * HB + PB);
  } else {
    S = (unsigned short*)d_out;  // S dead before K4 writes out
  }

  k_prep<<<dim3(SEQ / 32, DIM / 32, NBATCH), 256, 0, stream>>>(x, xh, xe, xT);
  k_scores<<<dim3(136, 1, NBATCH), 256, 0, stream>>>(xh, xe, S);
  k_softmax<<<NBATCH * SEQ / 4, 256, 0, stream>>>(S, mask, P);
  k_context<<<dim3(256, 1, 1), 512, 0, stream>>>(P, xT, x, out);
}

// Round 16
// 250.172 us; speedup vs baseline: 1.5187x; 1.3383x over previous
//
#include <hip/hip_runtime.h>
#include <hip/hip_bf16.h>

// Biattention: x:[8,2048,1024] f32, mask:[8,2048] i32
// out = concat([x, c, x+c, x-c, x*c], -1) where c = softmax(mask(x x^T)) x
//
// R16 = R15 + SINGLE-PASS fp16 scores: S = h h^T (K=1024, was symmetrized
// 2-pass K=2048). Error budget (measured ladder R11:0.156 -> R12:0.181):
// single-pass adds ~0.013 RMS logit err (same order as fp16-S storage
// already present); diagonal-dominated rows are inert. Predicted absmax
// 0.22-0.38 vs threshold 0.5125. Scores NT 64->32 (-50% FLOPs); prep drops
// the e-stream. All else R15-exact (incl. nontemporal context epilogue).

typedef __attribute__((ext_vector_type(8))) _Float16 half8;
typedef __attribute__((ext_vector_type(8))) unsigned short ushort8;
typedef __attribute__((ext_vector_type(4))) float f32x4;

#define SEQ 2048
#define DIM 1024
#define NBATCH 8
#define BK 32

__device__ __forceinline__ unsigned short f2h(float f) {
  union { _Float16 h; unsigned short u; } cv;
  cv.h = (_Float16)f;
  return cv.u;
}
__device__ __forceinline__ float h2f(unsigned short u) {
  union { _Float16 h; unsigned short u; } cv;
  cv.u = u;
  return (float)cv.h;
}

__device__ __forceinline__ void load16(const void* g, void* l) {
  __builtin_amdgcn_global_load_lds(
      (const __attribute__((address_space(1))) unsigned int*)g,
      (__attribute__((address_space(3))) unsigned int*)l, 16, 0, 0);
}

// ---------------- K1: convert + transpose (fp16; emits h, hT) ----------------
__global__ __launch_bounds__(256) void k_prep(
    const float* __restrict__ x, unsigned short* __restrict__ xh,
    unsigned short* __restrict__ xT) {
  __shared__ unsigned short tile[32][33];
  int b = blockIdx.z;
  int s0 = blockIdx.x * 32;
  int d0 = blockIdx.y * 32;
  int t = threadIdx.x;
  int r = t >> 3;
  int c4 = (t & 7) * 4;

  long src = (long)(b * SEQ + s0 + r) * DIM + d0 + c4;
  float4 v = *(const float4*)(x + src);
  float vv[4] = {v.x, v.y, v.z, v.w};
  unsigned short hu[4];
#pragma unroll
  for (int j = 0; j < 4; ++j) {
    hu[j] = f2h(vv[j]);
    tile[r][c4 + j] = hu[j];
  }
  *(ushort4*)(xh + src) = make_ushort4(hu[0], hu[1], hu[2], hu[3]);
  __syncthreads();
  unsigned short tv[4];
#pragma unroll
  for (int j = 0; j < 4; ++j) tv[j] = tile[c4 + j][r];
  long dst = (long)(b * DIM + d0 + r) * SEQ + s0 + c4;
  *(ushort4*)(xT + dst) = make_ushort4(tv[0], tv[1], tv[2], tv[3]);
}

// shared compute macro (R5-exact structure, f16 MFMA) — used by k_scores
#define COMPUTE_TILE(ARR_A, ARR_B, BUF)                                     \
  {                                                                         \
    half8 af[4], bg[4];                                                     \
    _Pragma("unroll") for (int m = 0; m < 4; ++m) {                         \
      int R = wr * 64 + m * 16 + l15;                                       \
      af[m] = *(const half8*)&ARR_A[BUF][R * BK + ((lhi ^ ((R >> 1) & 3)) * 8)]; \
    }                                                                       \
    _Pragma("unroll") for (int n = 0; n < 4; ++n) {                         \
      int R = wc * 64 + n * 16 + l15;                                       \
      bg[n] = *(const half8*)&ARR_B[BUF][R * BK + ((lhi ^ ((R >> 1) & 3)) * 8)]; \
    }                                                                       \
    _Pragma("unroll") for (int m = 0; m < 4; ++m)                           \
      _Pragma("unroll") for (int n = 0; n < 4; ++n)                         \
        acc[m][n] = __builtin_amdgcn_mfma_f32_16x16x32_f16(af[m], bg[n], acc[m][n], 0, 0, 0); \
  }

// ---------------- K2: scores GEMM (128^2, single-pass h h^T, d3) ----------------
#define NT_SC 32
__global__ __launch_bounds__(256) void k_scores(
    const unsigned short* __restrict__ xh, unsigned short* __restrict__ S) {
  __shared__ unsigned short As[3][128 * BK];
  __shared__ unsigned short Bs[3][128 * BK];
  int p = blockIdx.x + 136 * blockIdx.z;   // 0..1087
  int b = p & 7;                            // one batch per XCD (T1)
  int t = p >> 3;                           // tri-index 0..135
  int bm = 0, rem = 16;
  while (t >= rem) { t -= rem; ++bm; --rem; }
  int bn = bm + t;
  int m0 = bm * 128;
  int n0 = bn * 128;
  const unsigned short* xh_b = xh + (long)b * SEQ * DIM;
  unsigned short* S_b = S + (long)b * SEQ * SEQ;

  int tid = threadIdx.x;
  int w = tid >> 6, lane = tid & 63;
  int wr = w >> 1, wc = w & 1;
  int l15 = lane & 15, lhi = lane >> 4;

  int cbase0 = w * 64, cbase1 = 256 + w * 64;
  int c0 = cbase0 + lane, c1 = cbase1 + lane;
  int row0 = c0 >> 2, row1 = c1 >> 2;
  long aoff0 = (long)(m0 + row0) * DIM + ((c0 & 3) ^ ((row0 >> 1) & 3)) * 8;
  long aoff1 = (long)(m0 + row1) * DIM + ((c1 & 3) ^ ((row1 >> 1) & 3)) * 8;
  long boff0 = (long)(n0 + row0) * DIM + ((c0 & 3) ^ ((row0 >> 1) & 3)) * 8;
  long boff1 = (long)(n0 + row1) * DIM + ((c1 & 3) ^ ((row1 >> 1) & 3)) * 8;

#define STAGE_SC(KT, BUF)                                                   \
  {                                                                         \
    int kk_ = (KT) * BK;                                                    \
    load16(xh_b + aoff0 + kk_, &As[BUF][cbase0 * 8]);                       \
    load16(xh_b + aoff1 + kk_, &As[BUF][cbase1 * 8]);                       \
    load16(xh_b + boff0 + kk_, &Bs[BUF][cbase0 * 8]);                       \
    load16(xh_b + boff1 + kk_, &Bs[BUF][cbase1 * 8]);                       \
  }

  f32x4 acc[4][4];
#pragma unroll
  for (int m = 0; m < 4; ++m)
#pragma unroll
    for (int n = 0; n < 4; ++n)
#pragma unroll
      for (int j = 0; j < 4; ++j) acc[m][n][j] = 0.0f;

  STAGE_SC(0, 0);
  STAGE_SC(1, 1);
  STAGE_SC(2, 2);
  int cur = 0;
  for (int kt = 0; kt < NT_SC - 2; ++kt) {
    asm volatile("s_waitcnt vmcnt(8)" ::: "memory");
    __builtin_amdgcn_s_barrier();
    __builtin_amdgcn_sched_barrier(0);
    COMPUTE_TILE(As, Bs, cur);
    __builtin_amdgcn_sched_barrier(0);
    __builtin_amdgcn_s_barrier();
    if (kt + 3 < NT_SC) STAGE_SC(kt + 3, cur);
    cur = (cur == 2) ? 0 : cur + 1;
  }
  asm volatile("s_waitcnt vmcnt(4)" ::: "memory");
  __builtin_amdgcn_s_barrier();
  COMPUTE_TILE(As, Bs, (NT_SC - 2) % 3);
  asm volatile("s_waitcnt vmcnt(0)" ::: "memory");
  __builtin_amdgcn_s_barrier();
  COMPUTE_TILE(As, Bs, (NT_SC - 1) % 3);

  // normal-orientation write (scalar fp16), S = acc
#pragma unroll
  for (int m = 0; m < 4; ++m)
#pragma unroll
    for (int n = 0; n < 4; ++n)
#pragma unroll
      for (int j = 0; j < 4; ++j) {
        int r = m0 + wr * 64 + m * 16 + lhi * 4 + j;
        int c = n0 + wc * 64 + n * 16 + l15;
        S_b[(long)r * SEQ + c] = f2h(acc[m][n][j]);
      }
  // transposed write for off-diagonal blocks
  if (bm != bn) {
#pragma unroll
    for (int m = 0; m < 4; ++m)
#pragma unroll
      for (int n = 0; n < 4; ++n) {
        int r0 = m0 + wr * 64 + m * 16 + lhi * 4;
        int c = n0 + wc * 64 + n * 16 + l15;
        *(ushort4*)&S_b[(long)c * SEQ + r0] = make_ushort4(
            f2h(acc[m][n][0]), f2h(acc[m][n][1]),
            f2h(acc[m][n][2]), f2h(acc[m][n][3]));
      }
  }
}

// ---------------- K3: masked softmax (fp16 in, fp16 out), wave per row ----------------
__global__ __launch_bounds__(256) void k_softmax(
    const unsigned short* __restrict__ S, const int* __restrict__ mask,
    unsigned short* __restrict__ P) {
  int w = threadIdx.x >> 6, lane = threadIdx.x & 63;
  long row = (long)blockIdx.x * 4 + w;
  int b = (int)(row >> 11);
  const unsigned short* Sp = S + row * SEQ;
  const int* mp = mask + b * SEQ;
  unsigned short* Pp = P + row * SEQ;

  float sv[32];
  float mx = -__builtin_inff();
#pragma unroll
  for (int ci = 0; ci < 4; ++ci) {
    int col = ci * 512 + lane * 8;
    ushort8 v = *(const ushort8*)(Sp + col);
    int4 ma = *(const int4*)(mp + col);
    int4 mb = *(const int4*)(mp + col + 4);
    int mk[8] = {ma.x, ma.y, ma.z, ma.w, mb.x, mb.y, mb.z, mb.w};
#pragma unroll
    for (int j = 0; j < 8; ++j) {
      float s = mk[j] ? h2f(v[j]) : -__builtin_inff();
      sv[ci * 8 + j] = s;
      mx = fmaxf(mx, s);
    }
  }
#pragma unroll
  for (int off = 32; off; off >>= 1) mx = fmaxf(mx, __shfl_xor(mx, off));
  float pv[32];
  float sum = 0.0f;
#pragma unroll
  for (int i = 0; i < 32; ++i) {
    pv[i] = expf(sv[i] - mx);
    sum += pv[i];
  }
#pragma unroll
  for (int off = 32; off; off >>= 1) sum += __shfl_xor(sum, off);
  float inv = 1.0f / sum;
#pragma unroll
  for (int ci = 0; ci < 4; ++ci) {
    int col = ci * 512 + lane * 8;
    ushort8 o;
#pragma unroll
    for (int j = 0; j < 8; ++j) o[j] = f2h(pv[ci * 8 + j] * inv);
    *(ushort8*)(Pp + col) = o;
  }
}

// ---------------- K4: context GEMM 256^2 BK=64, 2 phases/tile (R15-exact) ----------------
#define NT_CTX 32
__global__ __launch_bounds__(512, 2) void k_context(
    const unsigned short* __restrict__ P, const unsigned short* __restrict__ xT,
    const float* __restrict__ x, float* __restrict__ out) {
  __shared__ unsigned short As[2 * 16384];  // 64 KB
  __shared__ unsigned short Bs[2 * 16384];  // 64 KB
  int p = blockIdx.x;            // 0..255
  int b = p & 7;                 // one batch per XCD (T1)
  int q = p >> 3;                // 0..31
  int n0 = (q & 3) * 256;        // d cols
  int m0 = (q >> 2) * 256;       // q rows
  const unsigned short* A_b = P + (long)b * SEQ * SEQ;
  const unsigned short* B_b = xT + (long)b * DIM * SEQ;

  int tid = threadIdx.x;
  int w = tid >> 6, lane = tid & 63;
  int wr = w >> 2, wc = w & 3;          // 2M x 4N waves; per-wave 128x64
  int l15 = lane & 15, lhi = lane >> 4;

  int c0 = w * 128 + lane, c1 = w * 128 + 64 + lane;
  int R0 = c0 >> 2, R1 = c1 >> 2;
  int sw0 = ((c0 & 3) ^ ((R0 >> 1) & 3)) * 8;
  int sw1 = ((c1 & 3) ^ ((R1 >> 1) & 3)) * 8;
  const unsigned short* PA0 = A_b + (long)(m0 + R0) * SEQ + sw0;
  const unsigned short* PA1 = A_b + (long)(m0 + R1) * SEQ + sw1;
  const unsigned short* PB0 = B_b + (long)(n0 + R0) * SEQ + sw0;
  const unsigned short* PB1 = B_b + (long)(n0 + R1) * SEQ + sw1;
  int ldg0 = (w * 128) * 8;
  int ldg1 = (w * 128 + 64) * 8;

#define STG_A(KT, KK, BUF)                                              \
  {                                                                     \
    load16(PA0 + (KT) * 64 + (KK) * 32, &As[(BUF)*16384 + (KK)*8192 + ldg0]); \
    load16(PA1 + (KT) * 64 + (KK) * 32, &As[(BUF)*16384 + (KK)*8192 + ldg1]); \
  }
#define STG_B(KT, KK, BUF)                                              \
  {                                                                     \
    load16(PB0 + (KT) * 64 + (KK) * 32, &Bs[(BUF)*16384 + (KK)*8192 + ldg0]); \
    load16(PB1 + (KT) * 64 + (KK) * 32, &Bs[(BUF)*16384 + (KK)*8192 + ldg1]); \
  }

  int swr = (lhi ^ ((l15 >> 1) & 3)) * 8;
  int arow = (wr * 128 + l15) * 32;
  int brow = (wc * 64 + l15) * 32;

  // one kk-half phase: read 12 frags, stage 4 loads, PH discipline, 32 MFMA
#define PHASE_CTX(BUF, KK, DO_STG_A, DO_STG_B, STKT, STKK, STBUF)             \
  {                                                                           \
    half8 af[8], bg[4];                                                       \
    _Pragma("unroll") for (int n = 0; n < 4; ++n)                             \
        bg[n] = *(const half8*)&Bs[(BUF)*16384 + (KK)*8192 + brow + n * 512 + swr]; \
    _Pragma("unroll") for (int m = 0; m < 8; ++m)                             \
        af[m] = *(const half8*)&As[(BUF)*16384 + (KK)*8192 + arow + m * 512 + swr]; \
    if (DO_STG_A) STG_A(STKT, STKK, STBUF);                                   \
    if (DO_STG_B) STG_B(STKT, STKK, STBUF);                                   \
    __builtin_amdgcn_s_barrier();                                             \
    asm volatile("s_waitcnt lgkmcnt(0)" ::: "memory");                        \
    __builtin_amdgcn_sched_barrier(0);                                        \
    __builtin_amdgcn_s_setprio(1);                                            \
    _Pragma("unroll") for (int m = 0; m < 8; ++m)                             \
      _Pragma("unroll") for (int n = 0; n < 4; ++n)                           \
        acc[m][n] = __builtin_amdgcn_mfma_f32_16x16x32_f16(                   \
            bg[n], af[m], acc[m][n], 0, 0, 0);                                \
    __builtin_amdgcn_s_setprio(0);                                            \
    __builtin_amdgcn_sched_barrier(0);                                        \
  }

  f32x4 acc[8][4];
#pragma unroll
  for (int m = 0; m < 8; ++m)
#pragma unroll
    for (int n = 0; n < 4; ++n)
#pragma unroll
      for (int j = 0; j < 4; ++j) acc[m][n][j] = 0.0f;

  // prologue: kt0 full (8 loads) + kt1 kk0 (4 loads); drain kt0 -> vmcnt(4)
  STG_A(0, 0, 0); STG_B(0, 0, 0);
  STG_A(0, 1, 0); STG_B(0, 1, 0);
  STG_A(1, 0, 1); STG_B(1, 0, 1);
  asm volatile("s_waitcnt vmcnt(4)" ::: "memory");
  __builtin_amdgcn_s_barrier();

  for (int kt = 0; kt < NT_CTX; ++kt) {
    int c = kt & 1, o = c ^ 1;
    int haveN1 = (kt + 1 < NT_CTX), haveN2 = (kt + 2 < NT_CTX);
    // phase A: compute kk0 of c; stage kt+1-kk1 -> o
    PHASE_CTX(c, 0, haveN1, haveN1, kt + 1, 1, o);
    __builtin_amdgcn_s_barrier();   // all waves done reading c-kk0
    // phase B: compute kk1 of c; stage kt+2-kk0 -> c (region just released)
    PHASE_CTX(c, 1, haveN2, haveN2, kt + 2, 0, c);
    if (kt < NT_CTX - 2) {
      asm volatile("s_waitcnt vmcnt(4)" ::: "memory");
    } else if (kt == NT_CTX - 2) {
      asm volatile("s_waitcnt vmcnt(0)" ::: "memory");
    }
    __builtin_amdgcn_s_barrier();
  }

  // epilogue: swapped-operand C layout -> thread holds 4 consecutive d (f32x4)
  // nontemporal: output is streamed once, never re-read
  const float* x_b = x + (long)b * SEQ * DIM;
  float* out_b = out + (long)b * SEQ * (5 * DIM);
#pragma unroll
  for (int m = 0; m < 8; ++m)
#pragma unroll
    for (int n = 0; n < 4; ++n) {
      int qi = m0 + wr * 128 + m * 16 + l15;      // col index = q
      int d = n0 + wc * 64 + n * 16 + lhi * 4;    // row index = d (4 consec)
      f32x4 c4 = acc[m][n];
      f32x4 xv = *(const f32x4*)&x_b[(long)qi * DIM + d];
      long base = (long)qi * (5 * DIM) + d;
      __builtin_nontemporal_store(xv,       (f32x4*)&out_b[base]);
      __builtin_nontemporal_store(c4,       (f32x4*)&out_b[base + DIM]);
      __builtin_nontemporal_store(xv + c4,  (f32x4*)&out_b[base + 2 * DIM]);
      __builtin_nontemporal_store(xv - c4,  (f32x4*)&out_b[base + 3 * DIM]);
      __builtin_nontemporal_store(xv * c4,  (f32x4*)&out_b[base + 4 * DIM]);
    }
}

extern "C" void kernel_launch(void* const* d_in, const int* in_sizes, int n_in,
                              void* d_out, int out_size, void* d_ws, size_t ws_size,
                              hipStream_t stream) {
  const float* x = (const float*)d_in[0];
  const int* mask = (const int*)d_in[1];
  float* out = (float*)d_out;
  char* ws = (char*)d_ws;

  const size_t HB = (size_t)NBATCH * SEQ * DIM * 2;
  unsigned short* xh = (unsigned short*)ws;
  unsigned short* xT = (unsigned short*)(ws + HB);
  unsigned short* P = (unsigned short*)(ws + 2 * HB);
  const size_t PB = (size_t)NBATCH * SEQ * SEQ * 2;
  const size_t SB = (size_t)NBATCH * SEQ * SEQ * 2;   // S fp16
  unsigned short* S;
  if (ws_size >= 2 * HB + PB + SB) {
    S = (unsigned short*)(ws + 2 * HB + PB);
  } else {
    S = (unsigned short*)d_out;  // S dead before K4 writes out
  }

  k_prep<<<dim3(SEQ / 32, DIM / 32, NBATCH), 256, 0, stream>>>(x, xh, xT);
  k_scores<<<dim3(136, 1, NBATCH), 256, 0, stream>>>(xh, S);
  k_softmax<<<NBATCH * SEQ / 4, 256, 0, stream>>>(S, mask, P);
  k_context<<<dim3(256, 1, 1), 512, 0, stream>>>(P, xT, x, out);
}